// Round 12
// baseline (381.369 us; speedup 1.0000x reference)
//
#include <hip/hip_runtime.h>

// GAE: h1 = relu(spmm(X@W1)); h2 = relu(spmm(h1@W2)); Z = spmm(h2@W3);
// A = sigmoid(Z @ Z^T).  Outputs: [A (12288x12288), Z (12288x16)] fp32, concat.
//
// DIAGNOSTIC ROUND: decode_mfma launched TWICE (identical writes) to measure
// decode's true duration as dur_us - 268. All else identical to R11.

constexpr int NN = 12288;   // nodes
constexpr int NE = 393216;  // edges
constexpr int KD = 1433;    // input dim
constexpr int CAP = 96;     // ELL row capacity (Poisson(32): P(deg>96) ~ 1e-18)

typedef float f32x4 __attribute__((ext_vector_type(4)));
typedef float f32x16 __attribute__((ext_vector_type(16)));
typedef short shortx8 __attribute__((ext_vector_type(8)));

// ---------------- fused: gemm1 (X@W1, LDS-tiled W) || ELL scatter ----------------
constexpr int KT = 256;
constexpr int G1B = NN / 64;  // 192 gemm blocks

__global__ __launch_bounds__(256) void k_scatter_gemm1(const int* __restrict__ er,
                                                       const int* __restrict__ ec,
                                                       const float* __restrict__ ev,
                                                       int* __restrict__ cnt,
                                                       uint2* __restrict__ ebuf,
                                                       const float* __restrict__ X,
                                                       const float* __restrict__ W,
                                                       float* __restrict__ out) {
    if (blockIdx.x >= G1B) {
        int e = (blockIdx.x - G1B) * 256 + threadIdx.x;
        int r = er[e];
        int p = atomicAdd(&cnt[r], 1);
        if (p < CAP) ebuf[(size_t)r * CAP + p] = make_uint2((unsigned)ec[e], __float_as_uint(ev[e]));
        return;
    }
    __shared__ float ws[KT * 32];
    int tid = threadIdx.x;
    int c4 = (tid & 7) * 4;
    int rs = tid >> 3;
    int r0 = blockIdx.x * 64 + rs;
    int r1 = r0 + 32;
    const float* x0 = X + (size_t)r0 * KD;
    const float* x1 = X + (size_t)r1 * KD;
    f32x4 acc0 = {0.f, 0.f, 0.f, 0.f};
    f32x4 acc1 = {0.f, 0.f, 0.f, 0.f};
    int phase = r0 & 3;
    int h = (4 - phase) & 3;

    for (int k0 = 0; k0 < KD; k0 += KT) {
        int kt = min(KT, KD - k0);
        __syncthreads();
        int n4 = (kt * 32) >> 2;
        for (int q = tid; q < n4; q += 256)
            *(f32x4*)(ws + q * 4) = *(const f32x4*)(W + (size_t)k0 * 32 + q * 4);
        __syncthreads();

        for (int kk = 0; kk < h; ++kk) {
            float a0 = x0[k0 + kk], a1 = x1[k0 + kk];
            const float* wr = ws + kk * 32 + c4;
#pragma unroll
            for (int j = 0; j < 4; ++j) { acc0[j] += a0 * wr[j]; acc1[j] += a1 * wr[j]; }
        }
        int nv = (kt - h) >> 2;
        const f32x4* p0 = (const f32x4*)(x0 + k0 + h);
        const f32x4* p1 = (const f32x4*)(x1 + k0 + h);
#pragma unroll 4
        for (int q = 0; q < nv; ++q) {
            f32x4 a0 = p0[q], a1 = p1[q];
            int kb = h + q * 4;
#pragma unroll
            for (int m = 0; m < 4; ++m) {
                f32x4 w4 = *(const f32x4*)(ws + (kb + m) * 32 + c4);
#pragma unroll
                for (int j = 0; j < 4; ++j) { acc0[j] += a0[m] * w4[j]; acc1[j] += a1[m] * w4[j]; }
            }
        }
        for (int kk = h + nv * 4; kk < kt; ++kk) {
            float a0 = x0[k0 + kk], a1 = x1[k0 + kk];
            const float* wr = ws + kk * 32 + c4;
#pragma unroll
            for (int j = 0; j < 4; ++j) { acc0[j] += a0 * wr[j]; acc1[j] += a1 * wr[j]; }
        }
    }
    *(f32x4*)(out + (size_t)r0 * 32 + c4) = acc0;
    *(f32x4*)(out + (size_t)r1 * 32 + c4) = acc1;
}

// ---------------- SpMM(ELL) + relu + dense GEMM, edge-split ----------------
template <int CO>
__global__ __launch_bounds__(256) void spmm_gemm(const float* __restrict__ in,
                                                 const float* __restrict__ Wm,
                                                 float* __restrict__ out,
                                                 const int* __restrict__ cnt,
                                                 const uint2* __restrict__ ebuf) {
    int tid = blockIdx.x * 256 + threadIdx.x;
    int r = tid >> 6;               // one wave per row
    int lane = threadIdx.x & 63;
    int c = lane & 31, half = lane >> 5;
    int co = c & (CO - 1);
    float wcol[32];
#pragma unroll
    for (int k = 0; k < 32; ++k) wcol[k] = Wm[k * CO + co];
    int deg = min(cnt[r], CAP);
    int mid = (deg >> 1) & ~1;      // even split point (eb4-aligned)
    int lo = half ? mid : 0;
    int hi = half ? deg : mid;
    const uint2* eb2 = ebuf + (size_t)r * CAP;
    const uint4* eb4 = (const uint4*)eb2;
    float acc = 0.f;
    int i = lo;
#pragma unroll 2
    for (; i + 4 <= hi; i += 4) {
        uint4 e01 = eb4[i >> 1], e23 = eb4[(i >> 1) + 1];
        acc += __uint_as_float(e01.y) * in[(size_t)e01.x * 32 + c];
        acc += __uint_as_float(e01.w) * in[(size_t)e01.z * 32 + c];
        acc += __uint_as_float(e23.y) * in[(size_t)e23.x * 32 + c];
        acc += __uint_as_float(e23.w) * in[(size_t)e23.z * 32 + c];
    }
    for (; i < hi; ++i) {
        uint2 e = eb2[i];
        acc += __uint_as_float(e.y) * in[(size_t)e.x * 32 + c];
    }
    float h = fmaxf(acc + __shfl_xor(acc, 32), 0.f);
    float o = 0.f;
#pragma unroll
    for (int k = 0; k < 32; ++k)
        o += __shfl(h, (lane & 32) + k) * wcol[k];
    if (half == 0 && c < CO) out[(size_t)r * CO + co] = o;
}

// ---------------- SpMM(ELL) width 16, edge-split -> Z (fp32) + Zb (bf16) ----------------
__global__ __launch_bounds__(256) void spmm16(const float* __restrict__ in,
                                              float* __restrict__ out,
                                              unsigned short* __restrict__ zb,
                                              const int* __restrict__ cnt,
                                              const uint2* __restrict__ ebuf) {
    int tid = blockIdx.x * 256 + threadIdx.x;
    int r = tid >> 5;
    int sub = tid & 31;
    int c = sub & 15, half = sub >> 4;
    int deg = min(cnt[r], CAP);
    int mid = (deg >> 1) & ~1;
    int lo = half ? mid : 0;
    int hi = half ? deg : mid;
    const uint2* eb2 = ebuf + (size_t)r * CAP;
    const uint4* eb4 = (const uint4*)eb2;
    float acc = 0.f;
    int i = lo;
#pragma unroll 2
    for (; i + 4 <= hi; i += 4) {
        uint4 e01 = eb4[i >> 1], e23 = eb4[(i >> 1) + 1];
        acc += __uint_as_float(e01.y) * in[(size_t)e01.x * 16 + c];
        acc += __uint_as_float(e01.w) * in[(size_t)e01.z * 16 + c];
        acc += __uint_as_float(e23.y) * in[(size_t)e23.x * 16 + c];
        acc += __uint_as_float(e23.w) * in[(size_t)e23.z * 16 + c];
    }
    for (; i < hi; ++i) {
        uint2 e = eb2[i];
        acc += __uint_as_float(e.y) * in[(size_t)e.x * 16 + c];
    }
    float s = acc + __shfl_xor(acc, 16);
    if (half == 0) {
        out[(size_t)r * 16 + c] = s;
        unsigned int bits = __float_as_uint(s);
        zb[(size_t)r * 16 + c] = (unsigned short)((bits + 0x7FFFu + ((bits >> 16) & 1u)) >> 16);
    }
}

// ---------------- decode via MFMA: A = sigmoid(Zb @ Zb^T) ----------------
// 128x128 tile / 4 waves; wave = 64x64 quadrant = 4x mfma_f32_32x32x16_bf16.
// A-frag: row=l&31, k=(l>>5)*8+j.  B-frag: col=l&31, k=(l>>5)*8+j.
// D (m74-verified): col=l&31, row=(q&3)+8*(q>>2)+4*(l>>5), q=0..15.
__global__ __launch_bounds__(256) void decode_mfma(const unsigned short* __restrict__ Zb,
                                                   float* __restrict__ A) {
    int id = blockIdx.x;
    int f = (id & 7) * (9216 / 8) + (id >> 3);   // XCD swizzle (bijective: 9216%8==0)
    int bi = f / 96, bj = f % 96;
    int w = threadIdx.x >> 6;
    int l = threadIdx.x & 63;
    int R = bi * 128 + (w >> 1) * 64;
    int C = bj * 128 + (w & 1) * 64;
    int lr = l & 31, lh = l >> 5;

    shortx8 a0 = *(const shortx8*)(Zb + ((size_t)(R + lr) << 4) + lh * 8);
    shortx8 a1 = *(const shortx8*)(Zb + ((size_t)(R + 32 + lr) << 4) + lh * 8);
    shortx8 b0 = *(const shortx8*)(Zb + ((size_t)(C + lr) << 4) + lh * 8);
    shortx8 b1 = *(const shortx8*)(Zb + ((size_t)(C + 32 + lr) << 4) + lh * 8);

    f32x16 acc00 = {0.f}, acc01 = {0.f}, acc10 = {0.f}, acc11 = {0.f};
    acc00 = __builtin_amdgcn_mfma_f32_32x32x16_bf16(a0, b0, acc00, 0, 0, 0);
    acc01 = __builtin_amdgcn_mfma_f32_32x32x16_bf16(a0, b1, acc01, 0, 0, 0);
    acc10 = __builtin_amdgcn_mfma_f32_32x32x16_bf16(a1, b0, acc10, 0, 0, 0);
    acc11 = __builtin_amdgcn_mfma_f32_32x32x16_bf16(a1, b1, acc11, 0, 0, 0);

#pragma unroll
    for (int q = 0; q < 16; ++q) {
        int rf = (q & 3) + 8 * (q >> 2) + 4 * lh;
        float s00 = __fdividef(1.0f, 1.0f + __expf(-acc00[q]));
        float s01 = __fdividef(1.0f, 1.0f + __expf(-acc01[q]));
        float s10 = __fdividef(1.0f, 1.0f + __expf(-acc10[q]));
        float s11 = __fdividef(1.0f, 1.0f + __expf(-acc11[q]));
        __builtin_nontemporal_store(s00, &A[(size_t)(R + rf) * NN + C + lr]);
        __builtin_nontemporal_store(s01, &A[(size_t)(R + rf) * NN + C + 32 + lr]);
        __builtin_nontemporal_store(s10, &A[(size_t)(R + 32 + rf) * NN + C + lr]);
        __builtin_nontemporal_store(s11, &A[(size_t)(R + 32 + rf) * NN + C + 32 + lr]);
    }
}

extern "C" void kernel_launch(void* const* d_in, const int* in_sizes, int n_in,
                              void* d_out, int out_size, void* d_ws, size_t ws_size,
                              hipStream_t stream) {
    const float* X  = (const float*)d_in[0];
    const float* W1 = (const float*)d_in[1];
    const float* W2 = (const float*)d_in[2];
    const float* W3 = (const float*)d_in[3];
    const float* ev = (const float*)d_in[4];
    const int*   er = (const int*)d_in[5];
    const int*   ec = (const int*)d_in[6];

    float* A = (float*)d_out;                 // [NN, NN]
    float* Z = A + (size_t)NN * NN;           // [NN, 16]

    float* t1 = (float*)d_ws;                 // [NN, 32]  X@W1; later Zb (bf16)
    float* t2 = t1 + (size_t)NN * 32;         // [NN, 32]
    float* t3 = t2 + (size_t)NN * 32;         // [NN, 16]
    int*   cnt = (int*)(t3 + (size_t)NN * 16);  // [NN]
    unsigned short* Zb = (unsigned short*)t1; // [NN, 16] bf16 (t1 dead by then)

    // ELL edge buffer in the tail of A (decode overwrites it last):
    // 9.4MB at 560MB offset; A is 604MB.
    uint2* ebuf = (uint2*)(A + (size_t)140000000);

    (void)hipMemsetAsync(cnt, 0, NN * sizeof(int), stream);

    // gemm1 (blocks 0..191) || ELL scatter (blocks 192..1727)
    k_scatter_gemm1<<<G1B + NE / 256, 256, 0, stream>>>(er, ec, ev, cnt, ebuf, X, W1, t1);

    // t2 = relu(spmm(t1)) @ W2   (one wave per row)
    spmm_gemm<32><<<NN * 64 / 256, 256, 0, stream>>>(t1, W2, t2, cnt, ebuf);
    // t3 = relu(spmm(t2)) @ W3
    spmm_gemm<16><<<NN * 64 / 256, 256, 0, stream>>>(t2, W3, t3, cnt, ebuf);
    // Z = spmm(t3); Zb = bf16(Z)   (32 lanes per row)
    spmm16<<<NN * 32 / 256, 256, 0, stream>>>(t3, Z, Zb, cnt, ebuf);

    // A = sigmoid(Z @ Z^T) via MFMA — launched TWICE (identical writes):
    // dur_us(this round) - 268 = decode's true duration. Diagnostic only.
    decode_mfma<<<96 * 96, 256, 0, stream>>>(Zb, A);
    decode_mfma<<<96 * 96, 256, 0, stream>>>(Zb, A);
}

// Round 13
// 237.861 us; speedup vs baseline: 1.6033x; 1.6033x over previous
//
#include <hip/hip_runtime.h>

// GAE: h1 = relu(spmm(X@W1)); h2 = relu(spmm(h1@W2)); Z = spmm(h2@W3);
// A = sigmoid(Z @ Z^T).  Outputs: [A (12288x12288), Z (12288x16)] fp32, concat.
//
// 6 dispatches: memset(cnt) -> [gemm1 || ELL-scatter] -> spmm+relu+@W2
//   -> spmm+relu+@W3 -> spmm16(+bf16) -> decode_mfma.
// R13: gemm1 at 1 row/thread (2x occupancy: 0.75 -> 1.5 waves/SIMD);
//      decode 64x256 tile with NT stores kept (geometry isolated from R10).

constexpr int NN = 12288;   // nodes
constexpr int NE = 393216;  // edges
constexpr int KD = 1433;    // input dim
constexpr int CAP = 96;     // ELL row capacity (Poisson(32): P(deg>96) ~ 1e-18)

typedef float f32x4 __attribute__((ext_vector_type(4)));
typedef float f32x16 __attribute__((ext_vector_type(16)));
typedef short shortx8 __attribute__((ext_vector_type(8)));

// ---------------- fused: gemm1 (X@W1, LDS-tiled W) || ELL scatter ----------------
constexpr int KT = 256;
constexpr int G1B = NN / 32;  // 384 gemm blocks, 32 rows each

__global__ __launch_bounds__(256) void k_scatter_gemm1(const int* __restrict__ er,
                                                       const int* __restrict__ ec,
                                                       const float* __restrict__ ev,
                                                       int* __restrict__ cnt,
                                                       uint2* __restrict__ ebuf,
                                                       const float* __restrict__ X,
                                                       const float* __restrict__ W,
                                                       float* __restrict__ out) {
    if (blockIdx.x >= G1B) {
        int e = (blockIdx.x - G1B) * 256 + threadIdx.x;
        int r = er[e];
        int p = atomicAdd(&cnt[r], 1);
        if (p < CAP) ebuf[(size_t)r * CAP + p] = make_uint2((unsigned)ec[e], __float_as_uint(ev[e]));
        return;
    }
    __shared__ float ws[KT * 32];
    int tid = threadIdx.x;
    int c4 = (tid & 7) * 4;        // 4 cols of 32
    int rs = tid >> 3;             // 0..31: row within block
    int r0 = blockIdx.x * 32 + rs;
    const float* x0 = X + (size_t)r0 * KD;
    f32x4 acc0 = {0.f, 0.f, 0.f, 0.f};
    int phase = r0 & 3;
    int h = (4 - phase) & 3;       // scalar head to reach 16B alignment

    for (int k0 = 0; k0 < KD; k0 += KT) {
        int kt = min(KT, KD - k0);
        __syncthreads();
        int n4 = (kt * 32) >> 2;
        for (int q = tid; q < n4; q += 256)
            *(f32x4*)(ws + q * 4) = *(const f32x4*)(W + (size_t)k0 * 32 + q * 4);
        __syncthreads();

        for (int kk = 0; kk < h; ++kk) {
            float a0 = x0[k0 + kk];
            const float* wr = ws + kk * 32 + c4;
#pragma unroll
            for (int j = 0; j < 4; ++j) acc0[j] += a0 * wr[j];
        }
        int nv = (kt - h) >> 2;
        const f32x4* p0 = (const f32x4*)(x0 + k0 + h);
#pragma unroll 4
        for (int q = 0; q < nv; ++q) {
            f32x4 a0 = p0[q];
            int kb = h + q * 4;
#pragma unroll
            for (int m = 0; m < 4; ++m) {
                f32x4 w4 = *(const f32x4*)(ws + (kb + m) * 32 + c4);
#pragma unroll
                for (int j = 0; j < 4; ++j) acc0[j] += a0[m] * w4[j];
            }
        }
        for (int kk = h + nv * 4; kk < kt; ++kk) {
            float a0 = x0[k0 + kk];
            const float* wr = ws + kk * 32 + c4;
#pragma unroll
            for (int j = 0; j < 4; ++j) acc0[j] += a0 * wr[j];
        }
    }
    *(f32x4*)(out + (size_t)r0 * 32 + c4) = acc0;
}

// ---------------- SpMM(ELL) + relu + dense GEMM, edge-split ----------------
template <int CO>
__global__ __launch_bounds__(256) void spmm_gemm(const float* __restrict__ in,
                                                 const float* __restrict__ Wm,
                                                 float* __restrict__ out,
                                                 const int* __restrict__ cnt,
                                                 const uint2* __restrict__ ebuf) {
    int tid = blockIdx.x * 256 + threadIdx.x;
    int r = tid >> 6;               // one wave per row
    int lane = threadIdx.x & 63;
    int c = lane & 31, half = lane >> 5;
    int co = c & (CO - 1);
    float wcol[32];
#pragma unroll
    for (int k = 0; k < 32; ++k) wcol[k] = Wm[k * CO + co];
    int deg = min(cnt[r], CAP);
    int mid = (deg >> 1) & ~1;      // even split point (eb4-aligned)
    int lo = half ? mid : 0;
    int hi = half ? deg : mid;
    const uint2* eb2 = ebuf + (size_t)r * CAP;
    const uint4* eb4 = (const uint4*)eb2;
    float acc = 0.f;
    int i = lo;
#pragma unroll 2
    for (; i + 4 <= hi; i += 4) {
        uint4 e01 = eb4[i >> 1], e23 = eb4[(i >> 1) + 1];
        acc += __uint_as_float(e01.y) * in[(size_t)e01.x * 32 + c];
        acc += __uint_as_float(e01.w) * in[(size_t)e01.z * 32 + c];
        acc += __uint_as_float(e23.y) * in[(size_t)e23.x * 32 + c];
        acc += __uint_as_float(e23.w) * in[(size_t)e23.z * 32 + c];
    }
    for (; i < hi; ++i) {
        uint2 e = eb2[i];
        acc += __uint_as_float(e.y) * in[(size_t)e.x * 32 + c];
    }
    float h = fmaxf(acc + __shfl_xor(acc, 32), 0.f);
    float o = 0.f;
#pragma unroll
    for (int k = 0; k < 32; ++k)
        o += __shfl(h, (lane & 32) + k) * wcol[k];
    if (half == 0 && c < CO) out[(size_t)r * CO + co] = o;
}

// ---------------- SpMM(ELL) width 16, edge-split -> Z (fp32) + Zb (bf16) ----------------
__global__ __launch_bounds__(256) void spmm16(const float* __restrict__ in,
                                              float* __restrict__ out,
                                              unsigned short* __restrict__ zb,
                                              const int* __restrict__ cnt,
                                              const uint2* __restrict__ ebuf) {
    int tid = blockIdx.x * 256 + threadIdx.x;
    int r = tid >> 5;
    int sub = tid & 31;
    int c = sub & 15, half = sub >> 4;
    int deg = min(cnt[r], CAP);
    int mid = (deg >> 1) & ~1;
    int lo = half ? mid : 0;
    int hi = half ? deg : mid;
    const uint2* eb2 = ebuf + (size_t)r * CAP;
    const uint4* eb4 = (const uint4*)eb2;
    float acc = 0.f;
    int i = lo;
#pragma unroll 2
    for (; i + 4 <= hi; i += 4) {
        uint4 e01 = eb4[i >> 1], e23 = eb4[(i >> 1) + 1];
        acc += __uint_as_float(e01.y) * in[(size_t)e01.x * 16 + c];
        acc += __uint_as_float(e01.w) * in[(size_t)e01.z * 16 + c];
        acc += __uint_as_float(e23.y) * in[(size_t)e23.x * 16 + c];
        acc += __uint_as_float(e23.w) * in[(size_t)e23.z * 16 + c];
    }
    for (; i < hi; ++i) {
        uint2 e = eb2[i];
        acc += __uint_as_float(e.y) * in[(size_t)e.x * 16 + c];
    }
    float s = acc + __shfl_xor(acc, 16);
    if (half == 0) {
        out[(size_t)r * 16 + c] = s;
        unsigned int bits = __float_as_uint(s);
        zb[(size_t)r * 16 + c] = (unsigned short)((bits + 0x7FFFu + ((bits >> 16) & 1u)) >> 16);
    }
}

// ---------------- decode via MFMA: A = sigmoid(Zb @ Zb^T) ----------------
// 64(i) x 256(j) tile / 4 waves side-by-side; wave = 64x64 = 4 MFMA.
// 1KB contiguous per A-row per block; NT scalar stores (2x128B lines/instr,
// bypass L2). bj-fastest XCD swizzle: same-XCD neighbors write adjacent
// column panels of the same row stripe.
// A-frag: row=l&31, k=(l>>5)*8+j.  B-frag: col=l&31, k=(l>>5)*8+j.
// D (m74-verified): col=l&31, row=(q&3)+8*(q>>2)+4*(l>>5), q=0..15.
__global__ __launch_bounds__(256) void decode_mfma(const unsigned short* __restrict__ Zb,
                                                   float* __restrict__ A) {
    int id = blockIdx.x;
    int f = (id & 7) * (9216 / 8) + (id >> 3);   // XCD swizzle (bijective: 9216%8==0)
    int bi = f / 48, bj = f % 48;                // 192 x 48 tiles of 64x256
    int w = threadIdx.x >> 6;
    int l = threadIdx.x & 63;
    int R = bi * 64;
    int C = bj * 256 + w * 64;
    int lr = l & 31, lh = l >> 5;

    shortx8 a0 = *(const shortx8*)(Zb + ((size_t)(R + lr) << 4) + lh * 8);
    shortx8 a1 = *(const shortx8*)(Zb + ((size_t)(R + 32 + lr) << 4) + lh * 8);
    shortx8 b0 = *(const shortx8*)(Zb + ((size_t)(C + lr) << 4) + lh * 8);
    shortx8 b1 = *(const shortx8*)(Zb + ((size_t)(C + 32 + lr) << 4) + lh * 8);

    f32x16 acc00 = {0.f}, acc01 = {0.f}, acc10 = {0.f}, acc11 = {0.f};
    acc00 = __builtin_amdgcn_mfma_f32_32x32x16_bf16(a0, b0, acc00, 0, 0, 0);
    acc01 = __builtin_amdgcn_mfma_f32_32x32x16_bf16(a0, b1, acc01, 0, 0, 0);
    acc10 = __builtin_amdgcn_mfma_f32_32x32x16_bf16(a1, b0, acc10, 0, 0, 0);
    acc11 = __builtin_amdgcn_mfma_f32_32x32x16_bf16(a1, b1, acc11, 0, 0, 0);

#pragma unroll
    for (int q = 0; q < 16; ++q) {
        int rf = (q & 3) + 8 * (q >> 2) + 4 * lh;
        float s00 = __fdividef(1.0f, 1.0f + __expf(-acc00[q]));
        float s01 = __fdividef(1.0f, 1.0f + __expf(-acc01[q]));
        float s10 = __fdividef(1.0f, 1.0f + __expf(-acc10[q]));
        float s11 = __fdividef(1.0f, 1.0f + __expf(-acc11[q]));
        __builtin_nontemporal_store(s00, &A[(size_t)(R + rf) * NN + C + lr]);
        __builtin_nontemporal_store(s01, &A[(size_t)(R + rf) * NN + C + 32 + lr]);
        __builtin_nontemporal_store(s10, &A[(size_t)(R + 32 + rf) * NN + C + lr]);
        __builtin_nontemporal_store(s11, &A[(size_t)(R + 32 + rf) * NN + C + 32 + lr]);
    }
}

extern "C" void kernel_launch(void* const* d_in, const int* in_sizes, int n_in,
                              void* d_out, int out_size, void* d_ws, size_t ws_size,
                              hipStream_t stream) {
    const float* X  = (const float*)d_in[0];
    const float* W1 = (const float*)d_in[1];
    const float* W2 = (const float*)d_in[2];
    const float* W3 = (const float*)d_in[3];
    const float* ev = (const float*)d_in[4];
    const int*   er = (const int*)d_in[5];
    const int*   ec = (const int*)d_in[6];

    float* A = (float*)d_out;                 // [NN, NN]
    float* Z = A + (size_t)NN * NN;           // [NN, 16]

    float* t1 = (float*)d_ws;                 // [NN, 32]  X@W1; later Zb (bf16)
    float* t2 = t1 + (size_t)NN * 32;         // [NN, 32]
    float* t3 = t2 + (size_t)NN * 32;         // [NN, 16]
    int*   cnt = (int*)(t3 + (size_t)NN * 16);  // [NN]
    unsigned short* Zb = (unsigned short*)t1; // [NN, 16] bf16 (t1 dead by then)

    // ELL edge buffer in the tail of A (decode overwrites it last):
    // 9.4MB at 560MB offset; A is 604MB.
    uint2* ebuf = (uint2*)(A + (size_t)140000000);

    (void)hipMemsetAsync(cnt, 0, NN * sizeof(int), stream);

    // gemm1 (blocks 0..383) || ELL scatter (blocks 384..1919)
    k_scatter_gemm1<<<G1B + NE / 256, 256, 0, stream>>>(er, ec, ev, cnt, ebuf, X, W1, t1);

    // t2 = relu(spmm(t1)) @ W2   (one wave per row)
    spmm_gemm<32><<<NN * 64 / 256, 256, 0, stream>>>(t1, W2, t2, cnt, ebuf);
    // t3 = relu(spmm(t2)) @ W3
    spmm_gemm<16><<<NN * 64 / 256, 256, 0, stream>>>(t2, W3, t3, cnt, ebuf);
    // Z = spmm(t3); Zb = bf16(Z)   (32 lanes per row)
    spmm16<<<NN * 32 / 256, 256, 0, stream>>>(t3, Z, Zb, cnt, ebuf);

    // A = sigmoid(Z @ Z^T) via MFMA
    decode_mfma<<<192 * 48, 256, 0, stream>>>(Zb, A);
}

// Round 14
// 218.894 us; speedup vs baseline: 1.7423x; 1.0866x over previous
//
#include <hip/hip_runtime.h>

// GAE: h1 = relu(spmm(X@W1)); h2 = relu(spmm(h1@W2)); Z = spmm(h2@W3);
// A = sigmoid(Z @ Z^T).  Outputs: [A (12288x12288), Z (12288x16)] fp32, concat.
//
// 6 dispatches: memset(cnt+t1) -> [gemm1 || ELL-scatter] -> spmm+relu+@W2
//   -> spmm+relu+@W3 -> spmm16(+bf16) -> decode_mfma.
// R14 gemm1: K-split x4 (12 waves/CU) + 2 rows/thread + unroll 8 ->
// ~24KB/CU outstanding X loads (HBM-saturating); atomicAdd epilogue into
// zero-init'd t1.

constexpr int NN = 12288;   // nodes
constexpr int NE = 393216;  // edges
constexpr int KD = 1433;    // input dim
constexpr int CAP = 96;     // ELL row capacity (Poisson(32): P(deg>96) ~ 1e-18)

typedef float f32x4 __attribute__((ext_vector_type(4)));
typedef float f32x16 __attribute__((ext_vector_type(16)));
typedef short shortx8 __attribute__((ext_vector_type(8)));

// ---------------- fused: gemm1 (X@W1, K-split, LDS W-tile) || ELL scatter ----------------
constexpr int KC = 384;        // K-chunk (48KB LDS tile; 1433 -> 384,384,384,281)
constexpr int G1B = (NN / 64) * 4;  // 192 row-groups x 4 K-chunks = 768 blocks

__global__ __launch_bounds__(256) void k_scatter_gemm1(const int* __restrict__ er,
                                                       const int* __restrict__ ec,
                                                       const float* __restrict__ ev,
                                                       int* __restrict__ cnt,
                                                       uint2* __restrict__ ebuf,
                                                       const float* __restrict__ X,
                                                       const float* __restrict__ W,
                                                       float* __restrict__ out) {
    if (blockIdx.x >= G1B) {
        int e = (blockIdx.x - G1B) * 256 + threadIdx.x;
        int r = er[e];
        int p = atomicAdd(&cnt[r], 1);
        if (p < CAP) ebuf[(size_t)r * CAP + p] = make_uint2((unsigned)ec[e], __float_as_uint(ev[e]));
        return;
    }
    __shared__ float ws[KC * 32];
    int rg = blockIdx.x >> 2;      // row group (64 rows)
    int s  = blockIdx.x & 3;       // K-chunk
    int k0 = s * KC;
    int kt = min(KC, KD - k0);
    int tid = threadIdx.x;
    int c4 = (tid & 7) * 4;        // 4 cols of 32
    int rs = tid >> 3;             // 0..31
    int r0 = rg * 64 + rs;
    int r1 = r0 + 32;
    const float* x0 = X + (size_t)r0 * KD;
    const float* x1 = X + (size_t)r1 * KD;
    f32x4 acc0 = {0.f, 0.f, 0.f, 0.f};
    f32x4 acc1 = {0.f, 0.f, 0.f, 0.f};
    int h = (4 - (r0 & 3)) & 3;    // (r*KD+k0)%4 == r%4 since KD%4==1, k0%4==0

    // stage W chunk
    int n4 = (kt * 32) >> 2;
    for (int q = tid; q < n4; q += 256)
        *(f32x4*)(ws + q * 4) = *(const f32x4*)(W + (size_t)k0 * 32 + q * 4);
    __syncthreads();

    for (int kk = 0; kk < h; ++kk) {
        float a0 = x0[k0 + kk], a1 = x1[k0 + kk];
        const float* wr = ws + kk * 32 + c4;
#pragma unroll
        for (int j = 0; j < 4; ++j) { acc0[j] += a0 * wr[j]; acc1[j] += a1 * wr[j]; }
    }
    int nv = (kt - h) >> 2;
    const f32x4* p0 = (const f32x4*)(x0 + k0 + h);
    const f32x4* p1 = (const f32x4*)(x1 + k0 + h);
#pragma unroll 8
    for (int q = 0; q < nv; ++q) {
        f32x4 a0 = p0[q], a1 = p1[q];
        int kb = h + q * 4;
#pragma unroll
        for (int m = 0; m < 4; ++m) {
            f32x4 w4 = *(const f32x4*)(ws + (kb + m) * 32 + c4);
#pragma unroll
            for (int j = 0; j < 4; ++j) { acc0[j] += a0[m] * w4[j]; acc1[j] += a1[m] * w4[j]; }
        }
    }
    for (int kk = h + nv * 4; kk < kt; ++kk) {
        float a0 = x0[k0 + kk], a1 = x1[k0 + kk];
        const float* wr = ws + kk * 32 + c4;
#pragma unroll
        for (int j = 0; j < 4; ++j) { acc0[j] += a0 * wr[j]; acc1[j] += a1 * wr[j]; }
    }
#pragma unroll
    for (int j = 0; j < 4; ++j) {
        atomicAdd(&out[(size_t)r0 * 32 + c4 + j], acc0[j]);
        atomicAdd(&out[(size_t)r1 * 32 + c4 + j], acc1[j]);
    }
}

// ---------------- SpMM(ELL) + relu + dense GEMM, edge-split ----------------
template <int CO>
__global__ __launch_bounds__(256) void spmm_gemm(const float* __restrict__ in,
                                                 const float* __restrict__ Wm,
                                                 float* __restrict__ out,
                                                 const int* __restrict__ cnt,
                                                 const uint2* __restrict__ ebuf) {
    int tid = blockIdx.x * 256 + threadIdx.x;
    int r = tid >> 6;               // one wave per row
    int lane = threadIdx.x & 63;
    int c = lane & 31, half = lane >> 5;
    int co = c & (CO - 1);
    float wcol[32];
#pragma unroll
    for (int k = 0; k < 32; ++k) wcol[k] = Wm[k * CO + co];
    int deg = min(cnt[r], CAP);
    int mid = (deg >> 1) & ~1;      // even split point (eb4-aligned)
    int lo = half ? mid : 0;
    int hi = half ? deg : mid;
    const uint2* eb2 = ebuf + (size_t)r * CAP;
    const uint4* eb4 = (const uint4*)eb2;
    float acc = 0.f;
    int i = lo;
#pragma unroll 2
    for (; i + 4 <= hi; i += 4) {
        uint4 e01 = eb4[i >> 1], e23 = eb4[(i >> 1) + 1];
        acc += __uint_as_float(e01.y) * in[(size_t)e01.x * 32 + c];
        acc += __uint_as_float(e01.w) * in[(size_t)e01.z * 32 + c];
        acc += __uint_as_float(e23.y) * in[(size_t)e23.x * 32 + c];
        acc += __uint_as_float(e23.w) * in[(size_t)e23.z * 32 + c];
    }
    for (; i < hi; ++i) {
        uint2 e = eb2[i];
        acc += __uint_as_float(e.y) * in[(size_t)e.x * 32 + c];
    }
    float h = fmaxf(acc + __shfl_xor(acc, 32), 0.f);
    float o = 0.f;
#pragma unroll
    for (int k = 0; k < 32; ++k)
        o += __shfl(h, (lane & 32) + k) * wcol[k];
    if (half == 0 && c < CO) out[(size_t)r * CO + co] = o;
}

// ---------------- SpMM(ELL) width 16, edge-split -> Z (fp32) + Zb (bf16) ----------------
__global__ __launch_bounds__(256) void spmm16(const float* __restrict__ in,
                                              float* __restrict__ out,
                                              unsigned short* __restrict__ zb,
                                              const int* __restrict__ cnt,
                                              const uint2* __restrict__ ebuf) {
    int tid = blockIdx.x * 256 + threadIdx.x;
    int r = tid >> 5;
    int sub = tid & 31;
    int c = sub & 15, half = sub >> 4;
    int deg = min(cnt[r], CAP);
    int mid = (deg >> 1) & ~1;
    int lo = half ? mid : 0;
    int hi = half ? deg : mid;
    const uint2* eb2 = ebuf + (size_t)r * CAP;
    const uint4* eb4 = (const uint4*)eb2;
    float acc = 0.f;
    int i = lo;
#pragma unroll 2
    for (; i + 4 <= hi; i += 4) {
        uint4 e01 = eb4[i >> 1], e23 = eb4[(i >> 1) + 1];
        acc += __uint_as_float(e01.y) * in[(size_t)e01.x * 16 + c];
        acc += __uint_as_float(e01.w) * in[(size_t)e01.z * 16 + c];
        acc += __uint_as_float(e23.y) * in[(size_t)e23.x * 16 + c];
        acc += __uint_as_float(e23.w) * in[(size_t)e23.z * 16 + c];
    }
    for (; i < hi; ++i) {
        uint2 e = eb2[i];
        acc += __uint_as_float(e.y) * in[(size_t)e.x * 16 + c];
    }
    float sv = acc + __shfl_xor(acc, 16);
    if (half == 0) {
        out[(size_t)r * 16 + c] = sv;
        unsigned int bits = __float_as_uint(sv);
        zb[(size_t)r * 16 + c] = (unsigned short)((bits + 0x7FFFu + ((bits >> 16) & 1u)) >> 16);
    }
}

// ---------------- decode via MFMA: A = sigmoid(Zb @ Zb^T) ----------------
// 64(i) x 256(j) tile / 4 waves side-by-side; wave = 64x64 = 4 MFMA.
// NT scalar stores; bj-fastest XCD swizzle.
// A-frag: row=l&31, k=(l>>5)*8+j.  B-frag: col=l&31, k=(l>>5)*8+j.
// D (m74-verified): col=l&31, row=(q&3)+8*(q>>2)+4*(l>>5), q=0..15.
__global__ __launch_bounds__(256) void decode_mfma(const unsigned short* __restrict__ Zb,
                                                   float* __restrict__ A) {
    int id = blockIdx.x;
    int f = (id & 7) * (9216 / 8) + (id >> 3);   // XCD swizzle (bijective: 9216%8==0)
    int bi = f / 48, bj = f % 48;                // 192 x 48 tiles of 64x256
    int w = threadIdx.x >> 6;
    int l = threadIdx.x & 63;
    int R = bi * 64;
    int C = bj * 256 + w * 64;
    int lr = l & 31, lh = l >> 5;

    shortx8 a0 = *(const shortx8*)(Zb + ((size_t)(R + lr) << 4) + lh * 8);
    shortx8 a1 = *(const shortx8*)(Zb + ((size_t)(R + 32 + lr) << 4) + lh * 8);
    shortx8 b0 = *(const shortx8*)(Zb + ((size_t)(C + lr) << 4) + lh * 8);
    shortx8 b1 = *(const shortx8*)(Zb + ((size_t)(C + 32 + lr) << 4) + lh * 8);

    f32x16 acc00 = {0.f}, acc01 = {0.f}, acc10 = {0.f}, acc11 = {0.f};
    acc00 = __builtin_amdgcn_mfma_f32_32x32x16_bf16(a0, b0, acc00, 0, 0, 0);
    acc01 = __builtin_amdgcn_mfma_f32_32x32x16_bf16(a0, b1, acc01, 0, 0, 0);
    acc10 = __builtin_amdgcn_mfma_f32_32x32x16_bf16(a1, b0, acc10, 0, 0, 0);
    acc11 = __builtin_amdgcn_mfma_f32_32x32x16_bf16(a1, b1, acc11, 0, 0, 0);

#pragma unroll
    for (int q = 0; q < 16; ++q) {
        int rf = (q & 3) + 8 * (q >> 2) + 4 * lh;
        float s00 = __fdividef(1.0f, 1.0f + __expf(-acc00[q]));
        float s01 = __fdividef(1.0f, 1.0f + __expf(-acc01[q]));
        float s10 = __fdividef(1.0f, 1.0f + __expf(-acc10[q]));
        float s11 = __fdividef(1.0f, 1.0f + __expf(-acc11[q]));
        __builtin_nontemporal_store(s00, &A[(size_t)(R + rf) * NN + C + lr]);
        __builtin_nontemporal_store(s01, &A[(size_t)(R + rf) * NN + C + 32 + lr]);
        __builtin_nontemporal_store(s10, &A[(size_t)(R + 32 + rf) * NN + C + lr]);
        __builtin_nontemporal_store(s11, &A[(size_t)(R + 32 + rf) * NN + C + 32 + lr]);
    }
}

extern "C" void kernel_launch(void* const* d_in, const int* in_sizes, int n_in,
                              void* d_out, int out_size, void* d_ws, size_t ws_size,
                              hipStream_t stream) {
    const float* X  = (const float*)d_in[0];
    const float* W1 = (const float*)d_in[1];
    const float* W2 = (const float*)d_in[2];
    const float* W3 = (const float*)d_in[3];
    const float* ev = (const float*)d_in[4];
    const int*   er = (const int*)d_in[5];
    const int*   ec = (const int*)d_in[6];

    float* A = (float*)d_out;                 // [NN, NN]
    float* Z = A + (size_t)NN * NN;           // [NN, 16]

    // ws layout: [cnt][t1][t2][t3] — cnt+t1 zeroed by ONE memset.
    int*   cnt = (int*)d_ws;                  // [NN]
    float* t1 = (float*)(cnt + NN);           // [NN, 32]  X@W1 (atomic-accum)
    float* t2 = t1 + (size_t)NN * 32;         // [NN, 32]
    float* t3 = t2 + (size_t)NN * 32;         // [NN, 16]
    unsigned short* Zb = (unsigned short*)t1; // [NN, 16] bf16 (t1 dead by then)

    // ELL edge buffer in the tail of A (decode overwrites it last):
    // 9.4MB at 560MB offset; A is 604MB.
    uint2* ebuf = (uint2*)(A + (size_t)140000000);

    // zero cnt + t1 (contiguous)
    (void)hipMemsetAsync(cnt, 0, NN * sizeof(int) + (size_t)NN * 32 * sizeof(float), stream);

    // gemm1 (blocks 0..767, K-split x4) || ELL scatter (blocks 768..2303)
    k_scatter_gemm1<<<G1B + NE / 256, 256, 0, stream>>>(er, ec, ev, cnt, ebuf, X, W1, t1);

    // t2 = relu(spmm(t1)) @ W2   (one wave per row)
    spmm_gemm<32><<<NN * 64 / 256, 256, 0, stream>>>(t1, W2, t2, cnt, ebuf);
    // t3 = relu(spmm(t2)) @ W3
    spmm_gemm<16><<<NN * 64 / 256, 256, 0, stream>>>(t2, W3, t3, cnt, ebuf);
    // Z = spmm(t3); Zb = bf16(Z)   (32 lanes per row)
    spmm16<<<NN * 32 / 256, 256, 0, stream>>>(t3, Z, Zb, cnt, ebuf);

    // A = sigmoid(Z @ Z^T) via MFMA
    decode_mfma<<<192 * 48, 256, 0, stream>>>(Zb, A);
}

// Round 15
// 213.395 us; speedup vs baseline: 1.7871x; 1.0258x over previous
//
#include <hip/hip_runtime.h>

// GAE: h1 = relu(spmm(X@W1)); h2 = relu(spmm(h1@W2)); Z = spmm(h2@W3);
// A = sigmoid(Z @ Z^T).  Outputs: [A (12288x12288), Z (12288x16)] fp32, concat.
//
// 6 dispatches: memset(cnt+t1) -> [gemm1-MFMA || ELL-scatter] -> spmm+relu+@W2
//   -> spmm+relu+@W3 -> spmm16(+bf16) -> decode_mfma.
// R15 gemm1: bf16 MFMA (32x32x16). Block = 64 rows x 256-k chunk; X and W1^T
// staged to bf16 LDS; 4 waves = 2 rowgroups x 2 k-halves; atomicAdd epilogue
// into zero-init'd t1. Beats the 29us wave64-FMA floor of the f32 path.

constexpr int NN = 12288;   // nodes
constexpr int NE = 393216;  // edges
constexpr int KD = 1433;    // input dim
constexpr int CAP = 96;     // ELL row capacity (Poisson(32): P(deg>96) ~ 1e-18)

typedef float f32x4 __attribute__((ext_vector_type(4)));
typedef float f32x16 __attribute__((ext_vector_type(16)));
typedef short shortx8 __attribute__((ext_vector_type(8)));

__device__ __forceinline__ unsigned short f2bf(float v) {
    unsigned int b = __float_as_uint(v);
    return (unsigned short)((b + 0x7FFFu + ((b >> 16) & 1u)) >> 16);
}

// ---------------- fused: gemm1 (X@W1 via MFMA, bf16) || ELL scatter ----------------
constexpr int KC = 256;              // k-chunk
constexpr int NCH = 6;               // ceil(1433/256) -> 256x5 + 153
constexpr int XST = KC + 8;          // LDS stride in bf16 (264: 4-way bank alias, ok)
constexpr int G1B = (NN / 64) * NCH; // 192 row-blocks x 6 chunks = 1152

__global__ __launch_bounds__(256) void k_scatter_gemm1(const int* __restrict__ er,
                                                       const int* __restrict__ ec,
                                                       const float* __restrict__ ev,
                                                       int* __restrict__ cnt,
                                                       uint2* __restrict__ ebuf,
                                                       const float* __restrict__ X,
                                                       const float* __restrict__ W,
                                                       float* __restrict__ out) {
    if (blockIdx.x >= G1B) {
        int e = (blockIdx.x - G1B) * 256 + threadIdx.x;
        int r = er[e];
        int p = atomicAdd(&cnt[r], 1);
        if (p < CAP) ebuf[(size_t)r * CAP + p] = make_uint2((unsigned)ec[e], __float_as_uint(ev[e]));
        return;
    }
    __shared__ unsigned short xs[64 * XST];  // X tile, bf16 [row][k]
    __shared__ unsigned short wt[32 * XST];  // W1^T tile, bf16 [col][k]

    int rgB   = blockIdx.x / NCH;        // row block (64 rows)
    int chunk = blockIdx.x % NCH;
    int r0 = rgB * 64;
    int k0 = chunk * KC;
    int kt = min(KC, KD - k0);           // 256 or 153
    int nm = (kt + 15) >> 4;             // mfma count along k (16 or 10)
    int t = threadIdx.x;

    // ---- stage W1^T (zero-padded to nm*16) ----
    int wtot = nm * 16 * 32;
    for (int e = t; e < wtot; e += 256) {
        int k = e >> 5, c = e & 31;
        float v = (k < kt) ? W[(size_t)(k0 + k) * 32 + c] : 0.f;
        wt[c * XST + k] = f2bf(v);
    }
    // ---- stage X (per-row alignment head/tail + zero pad) ----
    {
        int r = t & 63, s = t >> 6;
        int row = r0 + r;
        const float* xr = X + (size_t)row * KD + k0;
        unsigned short* xrow = xs + r * XST;
        int h = (4 - (row & 3)) & 3;     // (row*KD + k0) % 4 == row % 4
        if (s == 0)
            for (int kk = 0; kk < h; ++kk) xrow[kk] = f2bf(xr[kk]);
        int nq = (kt - h) >> 2;
        const f32x4* xq = (const f32x4*)(xr + h);
        for (int q = s; q < nq; q += 4) {
            f32x4 v = xq[q];
            int kb = h + q * 4;
            xrow[kb + 0] = f2bf(v[0]);
            xrow[kb + 1] = f2bf(v[1]);
            xrow[kb + 2] = f2bf(v[2]);
            xrow[kb + 3] = f2bf(v[3]);
        }
        if (s == 1)
            for (int kk = h + nq * 4; kk < kt; ++kk) xrow[kk] = f2bf(xr[kk]);
        if (s == 2)
            for (int kk = kt; kk < nm * 16; ++kk) xrow[kk] = 0;
    }
    __syncthreads();

    // ---- MFMA: wave w = rowgroup (w>>1) x k-half (w&1) ----
    int w = t >> 6, l = t & 63;
    int rg = w >> 1;
    int lr = l & 31, lh = l >> 5;
    const unsigned short* xbase = xs + (rg * 32 + lr) * XST + lh * 8;
    const unsigned short* wbase = wt + lr * XST + lh * 8;
    f32x16 acc = {0.f};
    for (int m = (w & 1); m < nm; m += 2) {
        shortx8 a = *(const shortx8*)(xbase + m * 16);
        shortx8 b = *(const shortx8*)(wbase + m * 16);
        acc = __builtin_amdgcn_mfma_f32_32x32x16_bf16(a, b, acc, 0, 0, 0);
    }
    // D: col=lr, row=(q&3)+8*(q>>2)+4*lh (m74-verified)
#pragma unroll
    for (int q = 0; q < 16; ++q) {
        int rf = (q & 3) + 8 * (q >> 2) + 4 * lh;
        atomicAdd(&out[(size_t)(r0 + rg * 32 + rf) * 32 + lr], acc[q]);
    }
}

// ---------------- SpMM(ELL) + relu + dense GEMM, edge-split ----------------
template <int CO>
__global__ __launch_bounds__(256) void spmm_gemm(const float* __restrict__ in,
                                                 const float* __restrict__ Wm,
                                                 float* __restrict__ out,
                                                 const int* __restrict__ cnt,
                                                 const uint2* __restrict__ ebuf) {
    int tid = blockIdx.x * 256 + threadIdx.x;
    int r = tid >> 6;               // one wave per row
    int lane = threadIdx.x & 63;
    int c = lane & 31, half = lane >> 5;
    int co = c & (CO - 1);
    float wcol[32];
#pragma unroll
    for (int k = 0; k < 32; ++k) wcol[k] = Wm[k * CO + co];
    int deg = min(cnt[r], CAP);
    int mid = (deg >> 1) & ~1;      // even split point (eb4-aligned)
    int lo = half ? mid : 0;
    int hi = half ? deg : mid;
    const uint2* eb2 = ebuf + (size_t)r * CAP;
    const uint4* eb4 = (const uint4*)eb2;
    float acc = 0.f;
    int i = lo;
#pragma unroll 2
    for (; i + 4 <= hi; i += 4) {
        uint4 e01 = eb4[i >> 1], e23 = eb4[(i >> 1) + 1];
        acc += __uint_as_float(e01.y) * in[(size_t)e01.x * 32 + c];
        acc += __uint_as_float(e01.w) * in[(size_t)e01.z * 32 + c];
        acc += __uint_as_float(e23.y) * in[(size_t)e23.x * 32 + c];
        acc += __uint_as_float(e23.w) * in[(size_t)e23.z * 32 + c];
    }
    for (; i < hi; ++i) {
        uint2 e = eb2[i];
        acc += __uint_as_float(e.y) * in[(size_t)e.x * 32 + c];
    }
    float h = fmaxf(acc + __shfl_xor(acc, 32), 0.f);
    float o = 0.f;
#pragma unroll
    for (int k = 0; k < 32; ++k)
        o += __shfl(h, (lane & 32) + k) * wcol[k];
    if (half == 0 && c < CO) out[(size_t)r * CO + co] = o;
}

// ---------------- SpMM(ELL) width 16, edge-split -> Z (fp32) + Zb (bf16) ----------------
__global__ __launch_bounds__(256) void spmm16(const float* __restrict__ in,
                                              float* __restrict__ out,
                                              unsigned short* __restrict__ zb,
                                              const int* __restrict__ cnt,
                                              const uint2* __restrict__ ebuf) {
    int tid = blockIdx.x * 256 + threadIdx.x;
    int r = tid >> 5;
    int sub = tid & 31;
    int c = sub & 15, half = sub >> 4;
    int deg = min(cnt[r], CAP);
    int mid = (deg >> 1) & ~1;
    int lo = half ? mid : 0;
    int hi = half ? deg : mid;
    const uint2* eb2 = ebuf + (size_t)r * CAP;
    const uint4* eb4 = (const uint4*)eb2;
    float acc = 0.f;
    int i = lo;
#pragma unroll 2
    for (; i + 4 <= hi; i += 4) {
        uint4 e01 = eb4[i >> 1], e23 = eb4[(i >> 1) + 1];
        acc += __uint_as_float(e01.y) * in[(size_t)e01.x * 16 + c];
        acc += __uint_as_float(e01.w) * in[(size_t)e01.z * 16 + c];
        acc += __uint_as_float(e23.y) * in[(size_t)e23.x * 16 + c];
        acc += __uint_as_float(e23.w) * in[(size_t)e23.z * 16 + c];
    }
    for (; i < hi; ++i) {
        uint2 e = eb2[i];
        acc += __uint_as_float(e.y) * in[(size_t)e.x * 16 + c];
    }
    float sv = acc + __shfl_xor(acc, 16);
    if (half == 0) {
        out[(size_t)r * 16 + c] = sv;
        zb[(size_t)r * 16 + c] = f2bf(sv);
    }
}

// ---------------- decode via MFMA: A = sigmoid(Zb @ Zb^T) ----------------
// 64(i) x 256(j) tile / 4 waves side-by-side; wave = 64x64 = 4 MFMA.
// NT scalar stores; bj-fastest XCD swizzle.
// A-frag: row=l&31, k=(l>>5)*8+j.  B-frag: col=l&31, k=(l>>5)*8+j.
// D (m74-verified): col=l&31, row=(q&3)+8*(q>>2)+4*(l>>5), q=0..15.
__global__ __launch_bounds__(256) void decode_mfma(const unsigned short* __restrict__ Zb,
                                                   float* __restrict__ A) {
    int id = blockIdx.x;
    int f = (id & 7) * (9216 / 8) + (id >> 3);   // XCD swizzle (bijective: 9216%8==0)
    int bi = f / 48, bj = f % 48;                // 192 x 48 tiles of 64x256
    int w = threadIdx.x >> 6;
    int l = threadIdx.x & 63;
    int R = bi * 64;
    int C = bj * 256 + w * 64;
    int lr = l & 31, lh = l >> 5;

    shortx8 a0 = *(const shortx8*)(Zb + ((size_t)(R + lr) << 4) + lh * 8);
    shortx8 a1 = *(const shortx8*)(Zb + ((size_t)(R + 32 + lr) << 4) + lh * 8);
    shortx8 b0 = *(const shortx8*)(Zb + ((size_t)(C + lr) << 4) + lh * 8);
    shortx8 b1 = *(const shortx8*)(Zb + ((size_t)(C + 32 + lr) << 4) + lh * 8);

    f32x16 acc00 = {0.f}, acc01 = {0.f}, acc10 = {0.f}, acc11 = {0.f};
    acc00 = __builtin_amdgcn_mfma_f32_32x32x16_bf16(a0, b0, acc00, 0, 0, 0);
    acc01 = __builtin_amdgcn_mfma_f32_32x32x16_bf16(a0, b1, acc01, 0, 0, 0);
    acc10 = __builtin_amdgcn_mfma_f32_32x32x16_bf16(a1, b0, acc10, 0, 0, 0);
    acc11 = __builtin_amdgcn_mfma_f32_32x32x16_bf16(a1, b1, acc11, 0, 0, 0);

#pragma unroll
    for (int q = 0; q < 16; ++q) {
        int rf = (q & 3) + 8 * (q >> 2) + 4 * lh;
        float s00 = __fdividef(1.0f, 1.0f + __expf(-acc00[q]));
        float s01 = __fdividef(1.0f, 1.0f + __expf(-acc01[q]));
        float s10 = __fdividef(1.0f, 1.0f + __expf(-acc10[q]));
        float s11 = __fdividef(1.0f, 1.0f + __expf(-acc11[q]));
        __builtin_nontemporal_store(s00, &A[(size_t)(R + rf) * NN + C + lr]);
        __builtin_nontemporal_store(s01, &A[(size_t)(R + rf) * NN + C + 32 + lr]);
        __builtin_nontemporal_store(s10, &A[(size_t)(R + 32 + rf) * NN + C + lr]);
        __builtin_nontemporal_store(s11, &A[(size_t)(R + 32 + rf) * NN + C + 32 + lr]);
    }
}

extern "C" void kernel_launch(void* const* d_in, const int* in_sizes, int n_in,
                              void* d_out, int out_size, void* d_ws, size_t ws_size,
                              hipStream_t stream) {
    const float* X  = (const float*)d_in[0];
    const float* W1 = (const float*)d_in[1];
    const float* W2 = (const float*)d_in[2];
    const float* W3 = (const float*)d_in[3];
    const float* ev = (const float*)d_in[4];
    const int*   er = (const int*)d_in[5];
    const int*   ec = (const int*)d_in[6];

    float* A = (float*)d_out;                 // [NN, NN]
    float* Z = A + (size_t)NN * NN;           // [NN, 16]

    // ws layout: [cnt][t1][t2][t3] — cnt+t1 zeroed by ONE memset.
    int*   cnt = (int*)d_ws;                  // [NN]
    float* t1 = (float*)(cnt + NN);           // [NN, 32]  X@W1 (atomic-accum)
    float* t2 = t1 + (size_t)NN * 32;         // [NN, 32]
    float* t3 = t2 + (size_t)NN * 32;         // [NN, 16]
    unsigned short* Zb = (unsigned short*)t1; // [NN, 16] bf16 (t1 dead by then)

    // ELL edge buffer in the tail of A (decode overwrites it last):
    // 9.4MB at 560MB offset; A is 604MB.
    uint2* ebuf = (uint2*)(A + (size_t)140000000);

    // zero cnt + t1 (contiguous)
    (void)hipMemsetAsync(cnt, 0, NN * sizeof(int) + (size_t)NN * 32 * sizeof(float), stream);

    // gemm1-MFMA (blocks 0..1151) || ELL scatter (blocks 1152..2687)
    k_scatter_gemm1<<<G1B + NE / 256, 256, 0, stream>>>(er, ec, ev, cnt, ebuf, X, W1, t1);

    // t2 = relu(spmm(t1)) @ W2   (one wave per row)
    spmm_gemm<32><<<NN * 64 / 256, 256, 0, stream>>>(t1, W2, t2, cnt, ebuf);
    // t3 = relu(spmm(t2)) @ W3
    spmm_gemm<16><<<NN * 64 / 256, 256, 0, stream>>>(t2, W3, t3, cnt, ebuf);
    // Z = spmm(t3); Zb = bf16(Z)   (32 lanes per row)
    spmm16<<<NN * 32 / 256, 256, 0, stream>>>(t3, Z, Zb, cnt, ebuf);

    // A = sigmoid(Z @ Z^T) via MFMA
    decode_mfma<<<192 * 48, 256, 0, stream>>>(Zb, A);
}